// Round 11
// baseline (40.380 us; speedup 1.0000x reference)
//
#include <hip/hip_runtime.h>
#include <math.h>
#include <float.h>
#include <limits.h>

#define MAXM 8192           // whole-batch pc1 staged in LDS
#define QPB  64             // queries per block (4 waves x 16)
#define NS   16             // stripes: lane s scans points p == s (mod 16)
#define NJ   8              // chunks per stripe (64 pts each) -> 128 chunks
#define CLEN 64             // points per chunk
#define MARGIN 0.05f
typedef unsigned long long ull;
#define KMAX 0xFFFFFFFFFFFFFFFFull

// padded LDS index: pidx(p) = p + (p>>4)  (one float4 pad per 16 points)
// -> stride-16 accesses step 17 float4s = 272B -> <=2-way bank aliasing (free)

// monotone float -> ordered u32 (handles negatives)
__device__ __forceinline__ unsigned int ford(float f) {
    unsigned int b = __float_as_uint(f);
    return b ^ (((unsigned int)((int)b >> 31)) | 0x80000000u);
}
__device__ __forceinline__ float funord(unsigned int u) {
    unsigned int m = ((u >> 31) - 1u) | 0x80000000u;
    return __uint_as_float(u ^ m);
}

__device__ __forceinline__ ull umin64(ull a, ull b) { return a < b ? a : b; }
__device__ __forceinline__ ull umax64(ull a, ull b) { return a > b ? a : b; }

// branchless sorted-3 insert on u64 keys (k0<=k1<=k2), lex (d,idx) tie-break
__device__ __forceinline__ void ins3k(ull k, ull& k0, ull& k1, ull& k2) {
    ull n2 = umax64(k1, umin64(k2, k));
    ull n1 = umax64(k0, umin64(k1, k));
    k0 = umin64(k0, k);
    k1 = n1;
    k2 = n2;
}

// branchless sorted-3 insert, f32 values only
__device__ __forceinline__ void sins(float d, float& a0, float& a1, float& a2)
{
    float n1 = __builtin_amdgcn_fmed3f(a0, a1, d);
    float n2 = __builtin_amdgcn_fmed3f(a1, a2, d);
    a0 = fminf(a0, d);
    a1 = n1;
    a2 = n2;
}

// pose_0to1 = inv(pose1) @ pose0 (SE3 analytic)
__device__ __forceinline__ void pose_rel(const float* __restrict__ P0,
                                         const float* __restrict__ P1,
                                         float R[3][3], float tv[3])
{
    float dt0 = P0[3]  - P1[3];
    float dt1 = P0[7]  - P1[7];
    float dt2 = P0[11] - P1[11];
    #pragma unroll
    for (int i = 0; i < 3; ++i) {
        float a0 = P1[i], a1 = P1[4 + i], a2 = P1[8 + i];   // col i of R1
        #pragma unroll
        for (int j = 0; j < 3; ++j)
            R[i][j] = fmaf(a2, P0[8 + j], fmaf(a1, P0[4 + j], a0 * P0[j]));
        tv[i] = fmaf(a2, dt2, fmaf(a1, dt1, a0 * dt0));
    }
}

__launch_bounds__(256, 1)
__global__ void knn_fused(const float* __restrict__ pc0,
                          const float* __restrict__ pc1,
                          const float* __restrict__ flow1,
                          const float* __restrict__ pose0,
                          const float* __restrict__ pose1,
                          float* __restrict__ out,
                          int B, int N, int M)
{
    __shared__ float4 tile[MAXM + (MAXM >> 4)];   // 139264 B, padded layout
    __shared__ float4 qd[QPB];                    // (qx,qy,qz,q2)

    const int tid = threadIdx.x;
    const int b   = blockIdx.y;
    const int qb  = blockIdx.x * QPB;

    // ---- stage 64 transformed queries + pose_flow ----
    if (tid < QPB) {
        float R[3][3], tv[3];
        pose_rel(pose0 + b * 16, pose1 + b * 16, R, tv);
        int qg0 = qb + tid;
        bool valid = qg0 < N;
        int qg = valid ? qg0 : (N - 1);
        const float px = pc0[(size_t)(b * N + qg) * 3 + 0];
        const float py = pc0[(size_t)(b * N + qg) * 3 + 1];
        const float pz = pc0[(size_t)(b * N + qg) * 3 + 2];
        float qx = fmaf(R[0][2], pz, fmaf(R[0][1], py, R[0][0] * px)) + tv[0];
        float qy = fmaf(R[1][2], pz, fmaf(R[1][1], py, R[1][0] * px)) + tv[1];
        float qz = fmaf(R[2][2], pz, fmaf(R[2][1], py, R[2][0] * px)) + tv[2];
        qd[tid] = make_float4(qx, qy, qz, (qx * qx + qy * qy) + qz * qz);
        if (valid) {
            size_t pf = (size_t)B * N * 3 + (size_t)(b * N + qg) * 3;
            out[pf + 0] = qx - px;
            out[pf + 1] = qy - py;
            out[pf + 2] = qz - pz;
        }
    }

    // ---- stage whole batch: 4 pts (3x dwordx4) per thread per round ----
    #pragma unroll
    for (int k = 0; k < MAXM / (256 * 4); ++k) {
        const int p0 = (tid + k * 256) * 4;
        // p0 % 4 == 0 -> the 4 points never straddle a 16-pt pad boundary
        float4* dst = &tile[p0 + (p0 >> 4)];
        if (p0 + 3 < M) {
            const float4* pf = (const float4*)(pc1 + (size_t)(b * M + p0) * 3);
            float4 A = pf[0], Bv = pf[1], C = pf[2];
            dst[0] = make_float4(-2.f * A.x, -2.f * A.y, -2.f * A.z,
                                 (A.x * A.x + A.y * A.y) + A.z * A.z);
            dst[1] = make_float4(-2.f * A.w, -2.f * Bv.x, -2.f * Bv.y,
                                 (A.w * A.w + Bv.x * Bv.x) + Bv.y * Bv.y);
            dst[2] = make_float4(-2.f * Bv.z, -2.f * Bv.w, -2.f * C.x,
                                 (Bv.z * Bv.z + Bv.w * Bv.w) + C.x * C.x);
            dst[3] = make_float4(-2.f * C.y, -2.f * C.z, -2.f * C.w,
                                 (C.y * C.y + C.z * C.z) + C.w * C.w);
        } else {
            #pragma unroll
            for (int u = 0; u < 4; ++u) {
                int pp = p0 + u;
                float4 v;
                if (pp < M) {
                    const float* s = pc1 + (size_t)(b * M + pp) * 3;
                    float x = s[0], y = s[1], z = s[2];
                    v = make_float4(-2.f * x, -2.f * y, -2.f * z,
                                    (x * x + y * y) + z * z);
                } else {
                    v = make_float4(0.f, 0.f, 0.f, FLT_MAX);
                }
                dst[u] = v;
            }
        }
    }
    __syncthreads();
    // no further barriers: all remaining phases are intra-wave

    const int lane = tid & 63;
    const int w    = tid >> 6;
    const int s    = lane & 15;     // stripe
    const int g    = lane >> 4;     // query group (4 queries)
    const int l    = s;             // lane within group

    // ---- scan: lane scans 512 pts (p = s + 16k) for its 4 queries ----
    float4 qv[4];
    #pragma unroll
    for (int t = 0; t < 4; ++t) qv[t] = qd[w * 16 + g * 4 + t];

    float mm[4][NJ];
    #pragma unroll
    for (int t = 0; t < 4; ++t)
        #pragma unroll
        for (int j = 0; j < NJ; ++j) mm[t][j] = FLT_MAX;

    const float4* tp = &tile[s];
    #pragma unroll
    for (int j = 0; j < NJ; ++j) {
        const float4* tpj = tp + j * (CLEN * 17);
        #pragma unroll 4
        for (int i = 0; i < CLEN; ++i) {
            const float4 v = tpj[i * 17];
            #pragma unroll
            for (int t = 0; t < 4; ++t)
                mm[t][j] = fminf(mm[t][j],
                    fmaf(qv[t].x, v.x, fmaf(qv[t].y, v.y, fmaf(qv[t].z, v.z, v.w))));
        }
    }

    // ---- per query: threshold, chunk mask, rescan, merge, outputs ----
    #pragma unroll
    for (int t = 0; t < 4; ++t) {
        // 3rd-smallest chunk-min: 8 in-lane + 4-level group butterfly
        float a0 = FLT_MAX, a1 = FLT_MAX, a2 = FLT_MAX;
        #pragma unroll
        for (int j = 0; j < NJ; ++j) sins(mm[t][j], a0, a1, a2);
        #pragma unroll
        for (int msk = 1; msk <= 8; msk <<= 1) {
            float o0 = __shfl_xor(a0, msk);
            float o1 = __shfl_xor(a1, msk);
            float o2 = __shfl_xor(a2, msk);
            sins(o0, a0, a1, a2);
            sins(o1, a0, a1, a2);
            sins(o2, a0, a1, a2);
        }
        const float thr = a2 + MARGIN;

        // chunk mask over 128 chunks (chunk id c = 8*s + j), 2x u64 OR-bfly
        unsigned int bits = 0;
        #pragma unroll
        for (int j = 0; j < NJ; ++j)
            bits |= (unsigned int)(mm[t][j] <= thr) << j;
        ull m0 = (s < 8) ? ((ull)bits << (8 * s)) : 0ull;
        ull m1 = (s >= 8) ? ((ull)bits << (8 * (s - 8))) : 0ull;
        #pragma unroll
        for (int msk = 1; msk <= 8; msk <<= 1) {
            m0 |= __shfl_xor(m0, msk);
            m1 |= __shfl_xor(m1, msk);
        }

        // exact rescan of selected chunks from LDS (16 lanes, 4 rounds/chunk)
        const float4 qq = qv[t];
        ull kA0 = KMAX, kA1 = KMAX, kA2 = KMAX;
        ull kB0 = KMAX, kB1 = KMAX, kB2 = KMAX;
        #pragma unroll
        for (int half = 0; half < 2; ++half) {
            ull mask = half ? m1 : m0;
            const int cb = half * 64;
            while (mask) {
                const int c  = cb + (int)__builtin_ctzll(mask);
                mask &= mask - 1;
                const int sc = c >> 3;          // chunk's stripe
                const int jc = c & 7;           // chunk-in-stripe
                #pragma unroll
                for (int r = 0; r < 4; ++r) {
                    const int kk_i = jc * CLEN + r * 16 + l;
                    const int p    = sc + 16 * kk_i;       // original index
                    const float4 v = tile[sc + 17 * kk_i]; // padded index
                    float t2 = fmaf(qq.z, v.z, fmaf(qq.y, v.y, qq.x * v.x));
                    float dd = (qq.w + v.w) + t2;   // == fmaf(-2,cross,q2+r2)
                    ull kk = ((ull)ford(dd) << 32) | (unsigned int)p;
                    if (r & 1) ins3k(kk, kB0, kB1, kB2);
                    else       ins3k(kk, kA0, kA1, kA2);
                }
            }
        }
        ins3k(kB0, kA0, kA1, kA2);
        ins3k(kB1, kA0, kA1, kA2);
        ins3k(kB2, kA0, kA1, kA2);

        // 4-level butterfly merge of sorted triples
        #pragma unroll
        for (int msk = 1; msk <= 8; msk <<= 1) {
            ull o0 = __shfl_xor(kA0, msk);
            ull o1 = __shfl_xor(kA1, msk);
            ull o2 = __shfl_xor(kA2, msk);
            ins3k(o0, kA0, kA1, kA2);
            ins3k(o1, kA0, kA1, kA2);
            ins3k(o2, kA0, kA1, kA2);
        }

        if (l == 0) {
            const int q0 = qb + w * 16 + g * 4 + t;
            if (q0 < N) {
                float D0 = funord((unsigned int)(kA0 >> 32));
                float D1 = funord((unsigned int)(kA1 >> 32));
                float D2 = funord((unsigned int)(kA2 >> 32));
                int   i0 = (int)(unsigned int)kA0;
                int   i1 = (int)(unsigned int)kA1;
                int   i2 = (int)(unsigned int)kA2;

                float dd0 = sqrtf(fmaxf(D0, 0.f));
                float dd1 = sqrtf(fmaxf(D1, 0.f));
                float dd2 = sqrtf(fmaxf(D2, 0.f));
                float w0 = 1.0f / (dd0 + 1e-8f);
                float w1 = 1.0f / (dd1 + 1e-8f);
                float w2 = 1.0f / (dd2 + 1e-8f);
                float wsum = (w0 + w1) + w2;
                w0 /= wsum; w1 /= wsum; w2 /= wsum;

                const float* f0 = flow1 + (size_t)(b * M + i0) * 3;
                const float* f1 = flow1 + (size_t)(b * M + i1) * 3;
                const float* f2 = flow1 + (size_t)(b * M + i2) * 3;

                const size_t ob = (size_t)(b * N + q0) * 3;
                #pragma unroll
                for (int ch = 0; ch < 3; ++ch) {
                    float p0 = w0 * f0[ch];
                    float p1 = w1 * f1[ch];
                    float p2 = w2 * f2[ch];
                    out[ob + ch] = (p0 + p1) + p2;
                }
            }
        }
    }
}

extern "C" void kernel_launch(void* const* d_in, const int* in_sizes, int n_in,
                              void* d_out, int out_size, void* d_ws, size_t ws_size,
                              hipStream_t stream) {
    const float* pc0   = (const float*)d_in[0];
    const float* pc1   = (const float*)d_in[1];
    const float* flow1 = (const float*)d_in[2];
    const float* pose0 = (const float*)d_in[3];
    const float* pose1 = (const float*)d_in[4];
    float* out = (float*)d_out;

    const int B = in_sizes[3] / 16;
    const int N = in_sizes[0] / (3 * B);
    const int M = in_sizes[1] / (3 * B);

    dim3 grid((N + QPB - 1) / QPB, B);
    knn_fused<<<grid, dim3(256), 0, stream>>>(pc0, pc1, flow1, pose0, pose1,
                                              out, B, N, M);
}

// Round 12
// 35.249 us; speedup vs baseline: 1.1456x; 1.1456x over previous
//
#include <hip/hip_runtime.h>
#include <math.h>
#include <float.h>
#include <limits.h>

#define CS   64             // points per chunk (selection granularity)
#define CT   32             // chunks per K1 block
#define TILE_PTS (CT * CS)  // 2048 staged points per K1 block
#define CSP  65             // padded chunk stride in float4
#define QB1  64             // queries per K1 block
#define QT   16             // queries per wave in K1
#define MARGIN 0.05f
typedef unsigned long long ull;
typedef float v2f __attribute__((ext_vector_type(2)));
#define KMAX 0xFFFFFFFFFFFFFFFFull

// monotone float -> ordered u32 (handles negatives)
__device__ __forceinline__ unsigned int ford(float f) {
    unsigned int b = __float_as_uint(f);
    return b ^ (((unsigned int)((int)b >> 31)) | 0x80000000u);
}
__device__ __forceinline__ float funord(unsigned int u) {
    unsigned int m = ((u >> 31) - 1u) | 0x80000000u;
    return __uint_as_float(u ^ m);
}

__device__ __forceinline__ ull umin64(ull a, ull b) { return a < b ? a : b; }
__device__ __forceinline__ ull umax64(ull a, ull b) { return a > b ? a : b; }

// branchless sorted-3 insert on u64 keys (k0<=k1<=k2)
__device__ __forceinline__ void ins3k(ull k, ull& k0, ull& k1, ull& k2) {
    ull n2 = umax64(k1, umin64(k2, k));   // med3(k1,k2,k)
    ull n1 = umax64(k0, umin64(k1, k));   // med3(k0,k1,k)
    k0 = umin64(k0, k);
    k1 = n1;
    k2 = n2;
}

// branchless sorted-3 insert, f32 values only
__device__ __forceinline__ void sins(float d, float& a0, float& a1, float& a2)
{
    float n1 = __builtin_amdgcn_fmed3f(a0, a1, d);
    float n2 = __builtin_amdgcn_fmed3f(a1, a2, d);
    a0 = fminf(a0, d);
    a1 = n1;
    a2 = n2;
}

// pose_0to1 = inv(pose1) @ pose0 (SE3 analytic)
__device__ __forceinline__ void pose_rel(const float* __restrict__ P0,
                                         const float* __restrict__ P1,
                                         float R[3][3], float tv[3])
{
    float dt0 = P0[3]  - P1[3];
    float dt1 = P0[7]  - P1[7];
    float dt2 = P0[11] - P1[11];
    #pragma unroll
    for (int i = 0; i < 3; ++i) {
        float a0 = P1[i], a1 = P1[4 + i], a2 = P1[8 + i];   // col i of R1
        #pragma unroll
        for (int j = 0; j < 3; ++j)
            R[i][j] = fmaf(a2, P0[8 + j], fmaf(a1, P0[4 + j], a0 * P0[j]));
        tv[i] = fmaf(a2, dt2, fmaf(a1, dt1, a0 * dt0));
    }
}

// ---------------- K1: per-(query, 64-pt chunk) key-min table ----------------
// key(q,m) = r2 - 2*cross  (q2 dropped: constant per query, order-preserving)
// LDS pair-interleaved: per point pair (A,B) two float4 records:
//   rec0 = (-2xA,-2xB,-2yA,-2yB)   rec1 = (-2zA,-2zB, rA, rB)
// so ds_read_b128 puts each component-pair in an aligned VGPR pair ->
// v_pk_fma_f32-able with zero shuffling.
__launch_bounds__(256, 3)
__global__ void knn_phaseA(const float* __restrict__ pc0,
                           const float* __restrict__ pc1,
                           const float* __restrict__ pose0,
                           const float* __restrict__ pose1,
                           float* __restrict__ cmin,
                           int B, int N, int M, int cstride)
{
    __shared__ float4 tile[CT * CSP];   // pair-interleaved, chunk-major padded
    __shared__ float4 qd[QB1];          // (qx,qy,qz,q2)

    const int tid = threadIdx.x;
    const int b   = blockIdx.z;
    const int ctb = blockIdx.y;               // chunk-tile index
    const int qb  = blockIdx.x * QB1;         // first query of block
    const int pbase = ctb * TILE_PTS;         // first staged point

    // ---- stage 64 transformed queries into LDS ----
    if (tid < QB1) {
        float R[3][3], tv[3];
        pose_rel(pose0 + b * 16, pose1 + b * 16, R, tv);
        int qg0 = qb + tid;
        int qg  = (qg0 < N) ? qg0 : (N - 1);
        const float px = pc0[(size_t)(b * N + qg) * 3 + 0];
        const float py = pc0[(size_t)(b * N + qg) * 3 + 1];
        const float pz = pc0[(size_t)(b * N + qg) * 3 + 2];
        float qx = fmaf(R[0][2], pz, fmaf(R[0][1], py, R[0][0] * px)) + tv[0];
        float qy = fmaf(R[1][2], pz, fmaf(R[1][1], py, R[1][0] * px)) + tv[1];
        float qz = fmaf(R[2][2], pz, fmaf(R[2][1], py, R[2][0] * px)) + tv[2];
        qd[tid] = make_float4(qx, qy, qz,
                              (qx * qx + qy * qy) + qz * qz);
    }

    // ---- stage 2048 points, 4 pts (3x dwordx4) per thread per round ----
    #pragma unroll
    for (int k = 0; k < TILE_PTS / (256 * 4); ++k) {
        const int pl = (tid + k * 256) * 4;   // local point, %4 == 0
        const int p  = pbase + pl;
        const int c  = pl >> 6;               // chunk
        const int off = pl & (CS - 1);        // offset in chunk, %4 == 0
        float4* dst = &tile[c * CSP + off];
        float x0,y0,z0, x1,y1,z1, x2,y2,z2, x3,y3,z3;
        if (p + 3 < M) {
            const float4* pf = (const float4*)(pc1 + (size_t)(b * M + p) * 3);
            float4 A = pf[0], Bv = pf[1], C = pf[2];
            x0 = A.x;  y0 = A.y;  z0 = A.z;
            x1 = A.w;  y1 = Bv.x; z1 = Bv.y;
            x2 = Bv.z; y2 = Bv.w; z2 = C.x;
            x3 = C.y;  y3 = C.z;  z3 = C.w;
        } else {
            float tx[4], ty[4], tz[4];
            #pragma unroll
            for (int u = 0; u < 4; ++u) {
                int pp = p + u;
                if (pp < M) {
                    const float* s = pc1 + (size_t)(b * M + pp) * 3;
                    tx[u] = s[0]; ty[u] = s[1]; tz[u] = s[2];
                } else {
                    tx[u] = 0.f; ty[u] = 0.f; tz[u] = 0.f;
                }
            }
            x0 = tx[0]; y0 = ty[0]; z0 = tz[0];
            x1 = tx[1]; y1 = ty[1]; z1 = tz[1];
            x2 = tx[2]; y2 = ty[2]; z2 = tz[2];
            x3 = tx[3]; y3 = ty[3]; z3 = tz[3];
        }
        float r0 = (p + 0 < M) ? (x0 * x0 + y0 * y0) + z0 * z0 : FLT_MAX;
        float r1 = (p + 1 < M) ? (x1 * x1 + y1 * y1) + z1 * z1 : FLT_MAX;
        float r2 = (p + 2 < M) ? (x2 * x2 + y2 * y2) + z2 * z2 : FLT_MAX;
        float r3 = (p + 3 < M) ? (x3 * x3 + y3 * y3) + z3 * z3 : FLT_MAX;
        dst[0] = make_float4(-2.f * x0, -2.f * x1, -2.f * y0, -2.f * y1);
        dst[1] = make_float4(-2.f * z0, -2.f * z1, r0, r1);
        dst[2] = make_float4(-2.f * x2, -2.f * x3, -2.f * y2, -2.f * y3);
        dst[3] = make_float4(-2.f * z2, -2.f * z3, r2, r3);
    }
    __syncthreads();

    // ---- scan: wave w handles 16 queries; lane = (part, chunk) ----
    const int w    = tid >> 6;
    const int lane = tid & 63;
    const int cl   = lane & 31;       // local chunk 0..31
    const int part = lane >> 5;       // half of the chunk (16 pairs)

    v2f qx2[QT], qy2[QT], qz2[QT];
    #pragma unroll
    for (int t = 0; t < QT; ++t) {
        float4 qq = qd[w * QT + t];
        qx2[t] = (v2f)(qq.x);
        qy2[t] = (v2f)(qq.y);
        qz2[t] = (v2f)(qq.z);
    }

    float mm[QT];
    #pragma unroll
    for (int t = 0; t < QT; ++t) mm[t] = FLT_MAX;

    // key(pair) = fma(X,qx, fma(Y,qy, fma(Z,qz, W))) per component —
    // identical rounding to R10's scalar fmaf chain (pk-fma is IEEE per lane).
    const float4* tp = &tile[cl * CSP + part * 32];
    #pragma unroll 2
    for (int i2 = 0; i2 < 16; ++i2) {
        const float4 xy = tp[2 * i2];
        const float4 zw = tp[2 * i2 + 1];
        v2f X = {xy.x, xy.y};
        v2f Y = {xy.z, xy.w};
        v2f Z = {zw.x, zw.y};
        v2f W = {zw.z, zw.w};
        #pragma unroll
        for (int t = 0; t < QT; ++t) {
            v2f kk = __builtin_elementwise_fma(Z, qz2[t], W);
            kk = __builtin_elementwise_fma(Y, qy2[t], kk);
            kk = __builtin_elementwise_fma(X, qx2[t], kk);
            mm[t] = fminf(mm[t], fminf(kk.x, kk.y));
        }
    }

    // merge the 2 parts of each chunk (lane bit 5); min is exact -> bit-identical
    #pragma unroll
    for (int t = 0; t < QT; ++t)
        mm[t] = fminf(mm[t], __shfl_xor(mm[t], 32));

    if (part == 0) {
        const int cg = ctb * CT + cl;         // global chunk id
        #pragma unroll
        for (int t = 0; t < QT; ++t) {
            int qg0 = qb + w * QT + t;
            int qg  = (qg0 < N) ? qg0 : (N - 1);
            cmin[((size_t)b * N + qg) * cstride + cg] = mm[t];
        }
    }
}

// ---------------- K2: threshold + exact rescan + outputs (R10 verbatim) ----------------
// 4 queries per wave, 16 lanes each (all reductions 4 levels, masks 1..8)
__launch_bounds__(256, 8)
__global__ void knn_select(const float* __restrict__ pc0,
                           const float* __restrict__ pc1,
                           const float* __restrict__ flow1,
                           const float* __restrict__ pose0,
                           const float* __restrict__ pose1,
                           const float* __restrict__ cmin,
                           float* __restrict__ out,
                           int B, int N, int M, int cstride)
{
    const int tid  = threadIdx.x;
    const int w    = tid >> 6;
    const int lane = tid & 63;
    const int g    = lane >> 4;        // query group in wave
    const int l    = lane & 15;        // lane within group
    const int b    = blockIdx.y;
    const int q0   = blockIdx.x * 16 + w * 4 + g;
    const bool qvalid = (q0 < N);
    const int q    = qvalid ? q0 : (N - 1);

    // ---- load this lane's 8 chunk-mins (2x dwordx4; table fully written) ----
    const size_t row = (size_t)(b * N + q) * cstride;
    const float4 sA = *(const float4*)&cmin[row + l * 8];
    const float4 sB = *(const float4*)&cmin[row + l * 8 + 4];

    // ---- query transform (redundant per lane) ----
    float R[3][3], tv[3];
    pose_rel(pose0 + b * 16, pose1 + b * 16, R, tv);
    const float px = pc0[(size_t)(b * N + q) * 3 + 0];
    const float py = pc0[(size_t)(b * N + q) * 3 + 1];
    const float pz = pc0[(size_t)(b * N + q) * 3 + 2];
    const float qx = fmaf(R[0][2], pz, fmaf(R[0][1], py, R[0][0] * px)) + tv[0];
    const float qy = fmaf(R[1][2], pz, fmaf(R[1][1], py, R[1][0] * px)) + tv[1];
    const float qz = fmaf(R[2][2], pz, fmaf(R[2][1], py, R[2][0] * px)) + tv[2];
    const float q2 = (qx * qx + qy * qy) + qz * qz;

    // ---- threshold: 3rd-smallest of 128 chunk-mins (8/lane + 4-level bfly) ----
    float a0 = FLT_MAX, a1 = FLT_MAX, a2 = FLT_MAX;
    sins(sA.x, a0, a1, a2); sins(sA.y, a0, a1, a2);
    sins(sA.z, a0, a1, a2); sins(sA.w, a0, a1, a2);
    sins(sB.x, a0, a1, a2); sins(sB.y, a0, a1, a2);
    sins(sB.z, a0, a1, a2); sins(sB.w, a0, a1, a2);
    #pragma unroll
    for (int msk = 1; msk <= 8; msk <<= 1) {
        float o0 = __shfl_xor(a0, msk);
        float o1 = __shfl_xor(a1, msk);
        float o2 = __shfl_xor(a2, msk);
        sins(o0, a0, a1, a2);
        sins(o1, a0, a1, a2);
        sins(o2, a0, a1, a2);
    }
    const float thr = a2 + MARGIN;

    // ---- two 64-bit chunk masks (chunks 0..63, 64..127), OR-butterfly ----
    unsigned int mbits =
          ((unsigned int)(sA.x <= thr) << 0) | ((unsigned int)(sA.y <= thr) << 1)
        | ((unsigned int)(sA.z <= thr) << 2) | ((unsigned int)(sA.w <= thr) << 3)
        | ((unsigned int)(sB.x <= thr) << 4) | ((unsigned int)(sB.y <= thr) << 5)
        | ((unsigned int)(sB.z <= thr) << 6) | ((unsigned int)(sB.w <= thr) << 7);
    ull m0 = (l < 8) ? ((ull)mbits << (8 * l)) : 0ull;
    ull m1 = (l >= 8) ? ((ull)mbits << (8 * (l - 8))) : 0ull;
    #pragma unroll
    for (int msk = 1; msk <= 8; msk <<= 1) {
        m0 |= __shfl_xor(m0, msk);
        m1 |= __shfl_xor(m1, msk);
    }

    // ---- dense rescan of selected 64-pt chunks from RAW pc1 ----
    // (validated exact path: never compute final dd from staged data)
    ull kA0 = KMAX, kA1 = KMAX, kA2 = KMAX;
    ull kB0 = KMAX, kB1 = KMAX, kB2 = KMAX;
    #pragma unroll
    for (int half = 0; half < 2; ++half) {
        ull mask = half ? m1 : m0;
        const int cbase = half * 64;
        while (mask) {
            const int ck = (int)__builtin_ctzll(mask);
            mask &= mask - 1;
            const int mb = (cbase + ck) * CS;
            #pragma unroll
            for (int r = 0; r < CS / 16; ++r) {
                const int m = mb + r * 16 + l;
                if (m < M) {
                    const float* pp = pc1 + (size_t)(b * M + m) * 3;
                    float x = pp[0], y = pp[1], z = pp[2];
                    float r2 = (x * x + y * y) + z * z;
                    float cr = fmaf(qz, z, fmaf(qy, y, qx * x));
                    float dd = fmaf(-2.0f, cr, q2 + r2);     // exact ref rounding
                    ull kk = ((ull)ford(dd) << 32) | (unsigned int)m;
                    if (r & 1) ins3k(kk, kB0, kB1, kB2);
                    else       ins3k(kk, kA0, kA1, kA2);
                }
            }
        }
    }
    ins3k(kB0, kA0, kA1, kA2);
    ins3k(kB1, kA0, kA1, kA2);
    ins3k(kB2, kA0, kA1, kA2);

    // ---- merge 16 lanes: 4-level butterfly of sorted triples ----
    #pragma unroll
    for (int msk = 1; msk <= 8; msk <<= 1) {
        ull o0 = __shfl_xor(kA0, msk);
        ull o1 = __shfl_xor(kA1, msk);
        ull o2 = __shfl_xor(kA2, msk);
        ins3k(o0, kA0, kA1, kA2);
        ins3k(o1, kA0, kA1, kA2);
        ins3k(o2, kA0, kA1, kA2);
    }

    if (l == 0 && qvalid) {
        // pose_flow
        size_t pf = (size_t)B * N * 3 + (size_t)(b * N + q) * 3;
        out[pf + 0] = qx - px;
        out[pf + 1] = qy - py;
        out[pf + 2] = qz - pz;

        float D0 = funord((unsigned int)(kA0 >> 32));
        float D1 = funord((unsigned int)(kA1 >> 32));
        float D2 = funord((unsigned int)(kA2 >> 32));
        int   i0 = (int)(unsigned int)kA0;
        int   i1 = (int)(unsigned int)kA1;
        int   i2 = (int)(unsigned int)kA2;

        float dd0 = sqrtf(fmaxf(D0, 0.f));
        float dd1 = sqrtf(fmaxf(D1, 0.f));
        float dd2 = sqrtf(fmaxf(D2, 0.f));
        float w0 = 1.0f / (dd0 + 1e-8f);
        float w1 = 1.0f / (dd1 + 1e-8f);
        float w2 = 1.0f / (dd2 + 1e-8f);
        float wsum = (w0 + w1) + w2;
        w0 /= wsum; w1 /= wsum; w2 /= wsum;

        const float* f0 = flow1 + (size_t)(b * M + i0) * 3;
        const float* f1 = flow1 + (size_t)(b * M + i1) * 3;
        const float* f2 = flow1 + (size_t)(b * M + i2) * 3;

        const size_t ob = (size_t)(b * N + q) * 3;
        #pragma unroll
        for (int c = 0; c < 3; ++c) {
            float p0 = w0 * f0[c];
            float p1 = w1 * f1[c];
            float p2 = w2 * f2[c];
            out[ob + c] = (p0 + p1) + p2;
        }
    }
}

extern "C" void kernel_launch(void* const* d_in, const int* in_sizes, int n_in,
                              void* d_out, int out_size, void* d_ws, size_t ws_size,
                              hipStream_t stream) {
    const float* pc0   = (const float*)d_in[0];
    const float* pc1   = (const float*)d_in[1];
    const float* flow1 = (const float*)d_in[2];
    const float* pose0 = (const float*)d_in[3];
    const float* pose1 = (const float*)d_in[4];
    float* out = (float*)d_out;

    const int B = in_sizes[3] / 16;
    const int N = in_sizes[0] / (3 * B);
    const int M = in_sizes[1] / (3 * B);

    const int nct     = (M + TILE_PTS - 1) / TILE_PTS;   // chunk-tiles
    const int cstride = nct * CT;                        // chunk-min row stride (128)

    float* cmin = (float*)d_ws;   // B*N*cstride floats (~8.4 MB at 2x8192x128)

    dim3 g1((N + QB1 - 1) / QB1, nct, B);
    knn_phaseA<<<g1, dim3(256), 0, stream>>>(pc0, pc1, pose0, pose1,
                                             cmin, B, N, M, cstride);

    dim3 g2((N + 15) / 16, B);
    knn_select<<<g2, dim3(256), 0, stream>>>(pc0, pc1, flow1, pose0, pose1,
                                             cmin, out, B, N, M, cstride);
}